// Round 8
// baseline (436.345 us; speedup 1.0000x reference)
//
#include <hip/hip_runtime.h>
#include <math.h>

constexpr int Bb   = 8;
constexpr int Cc   = 192;
constexpr int Hh   = 32;
constexpr int Ww   = 48;
constexpr int NPIX = 1536;
constexpr int S    = 12288;

typedef __attribute__((ext_vector_type(8))) short s16x8;
typedef __attribute__((ext_vector_type(4))) float f32x4;
typedef unsigned short u16;
typedef unsigned int   u32;

#define LRELU(v) ((v) >= 0.0f ? (v) : 0.2f * (v))

__device__ __forceinline__ u16 f2b(float x) {
    __bf16 h = (__bf16)x;
    return *reinterpret_cast<u16*>(&h);
}

// global -> LDS async 16B/lane; dest = wave-uniform base + lane*16 (linear)
__device__ __forceinline__ void gload(const u16* g, u16* l) {
    __builtin_amdgcn_global_load_lds(
        (const __attribute__((address_space(1))) unsigned int*)g,
        (__attribute__((address_space(3))) unsigned int*)l, 16, 0, 0);
}

// ---------------------------------------------------------------------------
// XT[s][384] bf16: cols 0..191 quantized y (exact), 192..383 ht
// ---------------------------------------------------------------------------
__global__ __launch_bounds__(256) void k_quantT(
    const float* __restrict__ y, const float* __restrict__ ht,
    u16* __restrict__ XT)
{
    __shared__ float ld[32][33];
    const int tx = threadIdx.x, ty = threadIdx.y;
    const int p0 = blockIdx.x * 32, c0 = blockIdx.y * 32;
    const int img = blockIdx.z >> 1, src = blockIdx.z & 1;
    const float* sp = (src ? ht : y) + (size_t)img * 192 * NPIX;
    #pragma unroll
    for (int k = 0; k < 4; ++k) {
        float v = sp[(size_t)(c0 + ty + 8 * k) * NPIX + p0 + tx];
        if (!src) v = fminf(fmaxf(floorf(v + 0.5f), -128.0f), 127.0f);
        ld[ty + 8 * k][tx] = v;
    }
    __syncthreads();
    #pragma unroll
    for (int k = 0; k < 4; ++k)
        XT[((size_t)img * NPIX + p0 + ty + 8 * k) * 384 + src * 192 + c0 + tx] =
            f2b(ld[tx][ty + 8 * k]);
}

// ---------------------------------------------------------------------------
// Weight packs, bf16 [n][K] row-major
// ---------------------------------------------------------------------------
__global__ void k_prep_w0nk(const float* __restrict__ w, u16* __restrict__ wt) {
    int i = blockIdx.x * 256 + threadIdx.x;           // 1728*384
    if (i >= 1728 * 384) return;
    int n = i / 384, ic = i % 384;
    int k = n / 192, oc = n % 192;
    wt[i] = f2b(w[(oc * 384 + ic) * 9 + k]);
}
__global__ void k_prep_w0yk(const float* __restrict__ w, u16* __restrict__ wt) {
    int i = blockIdx.x * 256 + threadIdx.x;           // 1152*192
    if (i >= 1152 * 192) return;
    int n = i / 192, ic = i % 192;
    int oc = n % 192, k = n / 192 + 3;
    wt[i] = f2b(w[(oc * 384 + ic) * 9 + k]);
}
__global__ void k_prep_w1pk(const float* __restrict__ w, u16* __restrict__ wt) {
    const int posflat[25] = {0,1,4,5, 1,2,3,5,6,7, 4,5,8,9,12,13,
                             5,6,7,9,10,11,13,14,15};
    int i = blockIdx.x * 256 + threadIdx.x;           // 921600
    if (i >= 921600) return;
    int z, r, K, sbase;
    if      (i < 147456) { z = 0; r = i;          K = 768;  sbase = 0;  }
    else if (i < 368640) { z = 1; r = i - 147456; K = 1152; sbase = 4;  }
    else if (i < 589824) { z = 2; r = i - 368640; K = 1152; sbase = 10; }
    else                 { z = 3; r = i - 589824; K = 1728; sbase = 16; }
    int n = r / K, k = r % K;
    int slab = k / 192, ic = k % 192;
    int pos = posflat[sbase + slab];
    int py = pos >> 2, px = pos & 3;
    int ki = py - 2 * (z >> 1) + 1, kj = px - 2 * (z & 1) + 1;
    wt[i] = f2b(w[(n * 192 + ic) * 9 + ki * 3 + kj]);
}
__global__ void k_prep_w2pk(const float* __restrict__ w, u16* __restrict__ wt) {
    int i = blockIdx.x * 256 + threadIdx.x;           // 768*768 (n=z*192+oc)
    if (i >= 589824) return;
    int z = i / 147456, r = i % 147456;
    int n = r / 768, k = r % 768;
    int pos = k / 192, ic = k % 192;
    int ki = (pos >> 1) - (z >> 1) + 1, kj = (pos & 1) - (z & 1) + 1;
    wt[i] = f2b(w[(n * 192 + ic) * 9 + ki * 3 + kj]);
}
__global__ void k_prep_fcpk(const float* __restrict__ w, u16* __restrict__ wt) {
    int i = blockIdx.x * 256 + threadIdx.x;           // 384*768
    if (i >= 384 * 768) return;
    int o = i / 768, fp = i % 768;
    int q = fp / 192, oc = fp % 192;
    wt[i] = f2b(w[o * 768 + oc * 4 + q]);
}
__global__ void k_prep_b2rep(const float* __restrict__ b, float* __restrict__ o) {
    int i = blockIdx.x * 256 + threadIdx.x;
    if (i < 768) o[i] = b[i % 192];
}

// ---------------------------------------------------------------------------
// Unified MFMA GEMM.  Y[s][yoff+n] = act(bias[n] + sum_k X[s][col(k)]*W[n][k])
// Block tile 128(s) x 192(n), BK=64, 4 waves 2x2, per-wave 64x96.
// Staging: global_load_lds w/ pre-swizzled source; reads XOR-swizzled.
// mode 0: lrelu + bf16;  1: fp32, no lrelu;  2: bf16, no bias/lrelu.
// ---------------------------------------------------------------------------
struct TDm { int K[4]; int woff[4]; int yoff[4]; int pm[4][9]; };

__global__ __launch_bounds__(256) void k_mgemm(
    const u16* __restrict__ X, int sx,
    const u16* __restrict__ Wb, const float* __restrict__ bias,
    void* __restrict__ Yb, int sy, int mode, TDm d)
{
    __shared__ u16 As[128 * 64];   // 16 KB, linear
    __shared__ u16 Bs[192 * 64];   // 24 KB, linear
    const int z = blockIdx.z;
    const int K = d.K[z];
    const u16* W = Wb + d.woff[z];
    const int tid = threadIdx.x;
    const int wv = tid >> 6, lane = tid & 63;
    const int wm = wv & 1, wn = wv >> 1;
    const int l15 = lane & 15, lk = lane >> 4;
    const int lr = lane >> 3, lc = lane & 7;
    const int sc = lc ^ lr;                 // pre-swizzled source chunk
    const int n0 = blockIdx.x * 192, s0 = blockIdx.y * 128;

    f32x4 acc[4][6];
    #pragma unroll
    for (int a = 0; a < 4; ++a)
        #pragma unroll
        for (int b = 0; b < 6; ++b) acc[a][b] = (f32x4){0, 0, 0, 0};

    int slab = 0, kin = 0;
    for (int k0 = 0; k0 < K; k0 += 64) {
        const int colA0 = d.pm[z][slab] * 192 + kin;
        // stage: A 16 stripes (8 rows x 128B each), B 24 stripes
        for (int st = wv; st < 40; st += 4) {
            if (st < 16) {
                const u16* g = X + (size_t)(s0 + st * 8 + lr) * sx + colA0 + sc * 8;
                gload(g, &As[st * 512]);
            } else {
                const int bs = st - 16;
                const u16* g = W + (size_t)(n0 + bs * 8 + lr) * K + k0 + sc * 8;
                gload(g, &Bs[bs * 512]);
            }
        }
        __syncthreads();   // drains vmcnt(0) before barrier

        #pragma unroll
        for (int ks = 0; ks < 2; ++ks) {
            s16x8 af[4], bf[6];
            #pragma unroll
            for (int mi = 0; mi < 4; ++mi) {
                const int r = wm * 64 + mi * 16 + l15;
                af[mi] = *reinterpret_cast<const s16x8*>(
                    &As[r * 64 + (((ks * 4 + lk) * 8) ^ ((l15 & 7) << 3))]);
            }
            #pragma unroll
            for (int ni = 0; ni < 6; ++ni) {
                const int r = wn * 96 + ni * 16 + l15;
                bf[ni] = *reinterpret_cast<const s16x8*>(
                    &Bs[r * 64 + (((ks * 4 + lk) * 8) ^ ((l15 & 7) << 3))]);
            }
            #pragma unroll
            for (int mi = 0; mi < 4; ++mi)
                #pragma unroll
                for (int ni = 0; ni < 6; ++ni)
                    acc[mi][ni] = __builtin_amdgcn_mfma_f32_16x16x32_bf16(
                        af[mi], bf[ni], acc[mi][ni], 0, 0, 0);
        }
        __syncthreads();
        kin += 64; if (kin == 192) { kin = 0; ++slab; }
    }

    #pragma unroll
    for (int mi = 0; mi < 4; ++mi)
        #pragma unroll
        for (int r = 0; r < 4; ++r) {
            const int srow = s0 + wm * 64 + mi * 16 + lk * 4 + r;
            #pragma unroll
            for (int ni = 0; ni < 6; ++ni) {
                const int ng = n0 + wn * 96 + ni * 16 + l15;
                float v = acc[mi][ni][r];
                if (mode != 2) v += bias[ng];
                if (mode == 0) {
                    v = LRELU(v);
                    ((u16*)Yb)[(size_t)srow * sy + d.yoff[z] + ng] = f2b(v);
                } else if (mode == 1) {
                    ((float*)Yb)[(size_t)srow * sy + ng] = v;
                } else {
                    ((u16*)Yb)[(size_t)srow * sy + ng] = f2b(v);
                }
            }
        }
}

// ---------------------------------------------------------------------------
// Assemble t0[s][pos*192+oc] bf16 from bf16 Hf/Hy partials (+bias, lrelu).
// 192 thr: 96 oc-pairs x 2 sample-groups; u32 (2xbf16) loads/stores.
// XCD-chunked block order for Hf L2 locality.
// ---------------------------------------------------------------------------
__global__ __launch_bounds__(192) void k_asm(
    const u16* __restrict__ Hf, const u16* __restrict__ Hy,
    const float* __restrict__ b0, u16* __restrict__ t0)
{
    const int cpx = gridDim.x >> 3;
    const int bid = (blockIdx.x & 7) * cpx + (blockIdx.x >> 3);
    const int t = threadIdx.x % 96, h = threadIdx.x / 96;
    const float bias0 = b0[2 * t], bias1 = b0[2 * t + 1];
    const u32* HF = (const u32*)Hf;
    const u32* HY = (const u32*)Hy;
    u32* T0 = (u32*)t0;
    for (int si = 0; si < 4; ++si) {
        const int s = bid * 8 + h * 4 + si;
        const int imgbase = (s / NPIX) * NPIX;
        const int p = s % NPIX;
        const int yy = p / Ww, xx = p % Ww;
        float a0[16], a1[16];
        #pragma unroll
        for (int i = 0; i < 16; ++i) { a0[i] = bias0; a1[i] = bias1; }
        #pragma unroll
        for (int py = 0; py < 4; ++py)
            #pragma unroll
            for (int px = 0; px < 4; ++px) {
                int Y = yy + py - 3, X = xx + px - 2;
                if ((unsigned)Y < (unsigned)Hh && (unsigned)X < (unsigned)Ww) {
                    const u32* hp = HF + (size_t)(imgbase + Y * Ww + X) * 864 + t;
                    #pragma unroll
                    for (int dy = -1; dy <= 1; ++dy) {
                        int oy = py - dy; if (oy < 0 || oy > 3) continue;
                        #pragma unroll
                        for (int dx = -1; dx <= 1; ++dx) {
                            int ox = px - dx; if (ox < 0 || ox > 3) continue;
                            u32 v = hp[((dy + 1) * 3 + dx + 1) * 96];
                            a0[oy * 4 + ox] += __uint_as_float(v << 16);
                            a1[oy * 4 + ox] += __uint_as_float(v & 0xffff0000u);
                        }
                    }
                }
            }
        {   // mask correction, patch (3,2): pixel = s
            const u32* yp = HY + (size_t)s * 576 + t;
            #pragma unroll
            for (int dy = 0; dy <= 1; ++dy)
                #pragma unroll
                for (int dx = -1; dx <= 1; ++dx) {
                    u32 v = yp[(dy * 3 + dx + 1) * 96];
                    a0[(3 - dy) * 4 + (2 - dx)] -= __uint_as_float(v << 16);
                    a1[(3 - dy) * 4 + (2 - dx)] -= __uint_as_float(v & 0xffff0000u);
                }
        }
        if (xx + 1 < Ww) {   // mask correction, patch (3,3): pixel = s+1
            const u32* yp = HY + (size_t)(s + 1) * 576 + t;
            #pragma unroll
            for (int dy = 0; dy <= 1; ++dy)
                #pragma unroll
                for (int dx = 0; dx <= 1; ++dx) {
                    u32 v = yp[(dy * 3 + dx + 1) * 96];
                    a0[(3 - dy) * 4 + (3 - dx)] -= __uint_as_float(v << 16);
                    a1[(3 - dy) * 4 + (3 - dx)] -= __uint_as_float(v & 0xffff0000u);
                }
        }
        u32* tr = T0 + (size_t)s * 1536 + t;
        #pragma unroll
        for (int pos = 0; pos < 16; ++pos) {
            float v0 = LRELU(a0[pos]), v1 = LRELU(a1[pos]);
            tr[pos * 96] = (u32)f2b(v0) | ((u32)f2b(v1) << 16);
        }
    }
}

// ---------------------------------------------------------------------------
// Likelihood into like[s][c], then transpose to out[b][c][p]
// ---------------------------------------------------------------------------
__global__ void k_like(const float* __restrict__ ctx, const u16* __restrict__ XT,
                       float* __restrict__ like)
{
    int i = blockIdx.x * 256 + threadIdx.x;
    if (i >= 192 * S) return;
    int s = i / 192, c = i % 192;
    float q  = __uint_as_float((u32)XT[(size_t)s * 384 + c] << 16);
    float mu = ctx[(size_t)s * 384 + c];
    float sg = expf(ctx[(size_t)s * 384 + 192 + c]);
    float inv = 1.0f / sg;
    float up = (q - mu + 0.5f) * inv;
    float lo = (q - mu - 0.5f) * inv;
    const float kc = 0.70710678118654752f;
    float lk = 0.5f * erfcf(-up * kc) - 0.5f * erfcf(-lo * kc);
    like[i] = fmaxf(lk, 1e-12f);
}

__global__ __launch_bounds__(256) void k_outT(
    const float* __restrict__ like, float* __restrict__ out)
{
    __shared__ float ld[32][33];
    const int tx = threadIdx.x, ty = threadIdx.y;
    const int p0 = blockIdx.x * 32, c0 = blockIdx.y * 32;
    const int img = blockIdx.z;
    #pragma unroll
    for (int k = 0; k < 4; ++k)
        ld[ty + 8 * k][tx] = like[((size_t)img * NPIX + p0 + ty + 8 * k) * 192 + c0 + tx];
    __syncthreads();
    #pragma unroll
    for (int k = 0; k < 4; ++k)
        out[((size_t)img * 192 + c0 + ty + 8 * k) * NPIX + p0 + tx] = ld[tx][ty + 8 * k];
}

// ---------------------------------------------------------------------------
extern "C" void kernel_launch(void* const* d_in, const int* in_sizes, int n_in,
                              void* d_out, int out_size, void* d_ws, size_t ws_size,
                              hipStream_t stream) {
    const float* y    = (const float*)d_in[0];
    const float* ht   = (const float*)d_in[1];
    const float* w0   = (const float*)d_in[2];
    const float* b0   = (const float*)d_in[3];
    const float* w1   = (const float*)d_in[4];
    const float* b1   = (const float*)d_in[5];
    const float* w2   = (const float*)d_in[6];
    const float* b2   = (const float*)d_in[7];
    const float* fcw  = (const float*)d_in[8];
    const float* fcb  = (const float*)d_in[9];
    float* out = (float*)d_out;

    // ---- workspace (byte offsets; total ~227 MB, proven >= 231 MB) ----
    char* ws = (char*)d_ws;
    u16*   XT    = (u16*)(ws);                   //  9,437,184
    u16*   w0nk  = (u16*)(ws + 9437184);         //  1,327,104
    u16*   w0yk  = (u16*)(ws + 10764288);        //    442,368
    u16*   w1pk  = (u16*)(ws + 11206656);        //  1,843,200
    u16*   w2pk  = (u16*)(ws + 13049856);        //  1,179,648
    u16*   fcpk  = (u16*)(ws + 14229504);        //    589,824
    float* b2rep = (float*)(ws + 14819328);      //      3,072
    u16*   Hf    = (u16*)(ws + 14822400);        // 42,467,328
    u16*   Hy    = (u16*)(ws + 57289728);        // 28,311,552
    u16*   t0    = (u16*)(ws + 85601280);        // 75,497,472
    u16*   t1    = (u16*)(ws + 161098752);       // 18,874,368
    u16*   t2    = (u16*)(ws + 179973120);       // 18,874,368
    float* ctx   = (float*)(ws + 198847488);     // 18,874,368
    float* like  = (float*)(ws + 217721856);     //  9,437,184 -> 227,159,040

    // ---- prep ----
    k_quantT<<<dim3(48, 6, 16), dim3(32, 8), 0, stream>>>(y, ht, XT);
    k_prep_w0nk<<<(1728 * 384 + 255) / 256, 256, 0, stream>>>(w0, w0nk);
    k_prep_w0yk<<<(1152 * 192 + 255) / 256, 256, 0, stream>>>(w0, w0yk);
    k_prep_w1pk<<<(921600 + 255) / 256, 256, 0, stream>>>(w1, w1pk);
    k_prep_w2pk<<<(589824 + 255) / 256, 256, 0, stream>>>(w2, w2pk);
    k_prep_fcpk<<<(384 * 768 + 255) / 256, 256, 0, stream>>>(fcw, fcpk);
    k_prep_b2rep<<<3, 256, 0, stream>>>(b2, b2rep);

    // ---- descriptors ----
    TDm dH = {}, dHy = {}, dB = {}, dC = {}, dD = {};
    dH.K[0] = 384;  dH.pm[0][0] = 0; dH.pm[0][1] = 1;
    dHy.K[0] = 192; dHy.pm[0][0] = 0;
    const int KB[4] = {768, 1152, 1152, 1728};
    const int wB[4] = {0, 147456, 368640, 589824};
    const int pmB[4][9] = {
        {0,1,4,5,0,0,0,0,0},
        {1,2,3,5,6,7,0,0,0},
        {4,5,8,9,12,13,0,0,0},
        {5,6,7,9,10,11,13,14,15}};
    for (int q = 0; q < 4; ++q) {
        dB.K[q] = KB[q]; dB.woff[q] = wB[q]; dB.yoff[q] = q * 192;
        for (int j = 0; j < 9; ++j) dB.pm[q][j] = pmB[q][j];
    }
    dC.K[0] = 768; for (int j = 0; j < 4; ++j) dC.pm[0][j] = j;
    dD.K[0] = 768; for (int j = 0; j < 4; ++j) dD.pm[0][j] = j;

    // ---- pipeline ----
    k_mgemm<<<dim3(9, 96, 1), 256, 0, stream>>>(XT, 384, w0nk, b0,   Hf, 1728, 2, dH);
    k_mgemm<<<dim3(6, 96, 1), 256, 0, stream>>>(XT, 384, w0yk, b0,   Hy, 1152, 2, dHy);
    k_asm<<<1536, 192, 0, stream>>>(Hf, Hy, b0, t0);
    k_mgemm<<<dim3(1, 96, 4), 256, 0, stream>>>(t0, 3072, w1pk, b1,    t1, 768, 0, dB);
    k_mgemm<<<dim3(4, 96, 1), 256, 0, stream>>>(t1, 768,  w2pk, b2rep, t2, 768, 0, dC);
    k_mgemm<<<dim3(2, 96, 1), 256, 0, stream>>>(t2, 768,  fcpk, fcb,  ctx, 384, 1, dD);
    k_like<<<(192 * S + 255) / 256, 256, 0, stream>>>(ctx, XT, like);
    k_outT<<<dim3(48, 6, 8), dim3(32, 8), 0, stream>>>(like, out);
}